// Round 10
// baseline (248.084 us; speedup 1.0000x reference)
//
#include <hip/hip_runtime.h>

#define N_NODES 50000
#define N_EDGES 800000
#define D 128
#define CAP 48      // bucket capacity per dst node (max in-degree ~45 for this dataset)
#define OVF_CAP 4096

#define BINS 40     // dst partitions
#define PNODES 1250 // nodes per partition = 50000/40
#define SN 625      // nodes per scatter2 block (2 blocks per bin)
#define B1 256      // binning blocks (hist40/place40 share chunking) -> 1 block/CU
#define CH1 ((N_EDGES + B1 - 1) / B1)   // 3125 edges per chunk
#define NW (N_NODES / 4)                // packed byte-counter words = 12500
#define WPB ((NW + B1 - 1) / B1)        // sreduce words per place40 block = 49

typedef unsigned short bf16_t;
typedef __attribute__((ext_vector_type(8))) short short8v;   // 8 bf16 = 4 VGPR (MFMA A/B frag)
typedef __attribute__((ext_vector_type(4))) float f32x4;     // MFMA C/D frag

__device__ inline float bf2f(bf16_t u) {
    union { unsigned int i; float f; } v;
    v.i = ((unsigned int)u) << 16;
    return v.f;
}
__device__ inline bf16_t f2bf(float f) {
    union { float f; unsigned int i; } v;
    v.f = f;
    unsigned int u = v.i;
    unsigned int r = (u + 0x7FFFu + ((u >> 16) & 1u)) >> 16;  // RNE
    return (bf16_t)r;
}
// bf16 pair packed in a u32 (little-endian: lo half = even col, hi half = odd col)
__device__ inline float u2f_lo(unsigned int u) {
    union { unsigned int i; float f; } x; x.i = u << 16; return x.f;
}
__device__ inline float u2f_hi(unsigned int u) {
    union { unsigned int i; float f; } x; x.i = u & 0xFFFF0000u; return x.f;
}

// =============== two-phase binned scatter (r7 structure, grid-destarved) ===============
// r9 evidence: hist40/place40 ran on 64 of 256 CUs; scatter2 on 40. B1=256 puts
// binning at 1 block/CU; scan40 becomes a parallel scan (serial x256 would be
// latency-bound); scatter2 splits each bin across 2 blocks (80 CUs).
__global__ __launch_bounds__(1024) void hist40_kernel(const int* __restrict__ src,
                                                      const int* __restrict__ dst,
                                                      unsigned int* __restrict__ H40,
                                                      unsigned int* __restrict__ SH,
                                                      int* __restrict__ ovf_cnt, int nE) {
    __shared__ unsigned int hb[BINS];
    __shared__ unsigned int hs[NW];   // 50 KB src byte counters
    if (blockIdx.x == 0 && threadIdx.x == 0) ovf_cnt[0] = 0;
    for (int i = threadIdx.x; i < NW; i += 1024) hs[i] = 0u;
    if (threadIdx.x < BINS) hb[threadIdx.x] = 0u;
    __syncthreads();
    int e0 = blockIdx.x * CH1;
    int e1 = min(e0 + CH1, nE);
    for (int e = e0 + (int)threadIdx.x; e < e1; e += 1024) {
        int s = src[e];
        int d = dst[e];
        atomicAdd(&hs[s >> 2], 1u << (8 * (s & 3)));   // per-chunk count < 256
        atomicAdd(&hb[d / PNODES], 1u);
    }
    __syncthreads();
    if (threadIdx.x < BINS) H40[blockIdx.x * BINS + threadIdx.x] = hb[threadIdx.x];
    unsigned int* SHb = SH + (size_t)blockIdx.x * NW;
    for (int i = threadIdx.x; i < NW; i += 1024) SHb[i] = hs[i];
}

// parallel scan over B1 chunks per bin: block = bin, Hillis-Steele in LDS
__global__ __launch_bounds__(B1) void scan40_kernel(const unsigned int* __restrict__ H40,
                                                    unsigned int* __restrict__ OFF40,
                                                    unsigned int* __restrict__ binTot) {
    __shared__ unsigned int sc[B1];
    int j = (int)blockIdx.x;
    int t = (int)threadIdx.x;
    unsigned int own = H40[t * BINS + j];
    sc[t] = own;
    __syncthreads();
    for (int off = 1; off < B1; off <<= 1) {
        unsigned int v = (t >= off) ? sc[t - off] : 0u;
        __syncthreads();
        sc[t] += v;
        __syncthreads();
    }
    OFF40[t * BINS + j] = sc[t] - own;   // exclusive prefix (within bin)
    if (t == B1 - 1) binTot[j] = sc[t];
}

__global__ __launch_bounds__(1024) void place40_kernel(const int* __restrict__ src,
                                                       const int* __restrict__ dst,
                                                       const unsigned int* __restrict__ OFF40,
                                                       const unsigned int* __restrict__ binTot,
                                                       unsigned int* __restrict__ binned,
                                                       const unsigned int* __restrict__ SH,
                                                       int* __restrict__ cnt_s, int nE) {
    __shared__ unsigned int cur[BINS];
    __shared__ unsigned int bb[BINS];
    int t = (int)threadIdx.x;
    if (t < BINS) bb[t] = binTot[t];
    __syncthreads();
    if (t == 0) {
        unsigned int r = 0;
        for (int q = 0; q < BINS; q++) { unsigned int v = bb[q]; bb[q] = r; r += v; }
    }
    __syncthreads();
    if (t < BINS) cur[t] = OFF40[blockIdx.x * BINS + t] + bb[t];
    __syncthreads();
    int e0 = blockIdx.x * CH1;
    int e1 = min(e0 + CH1, nE);
    for (int e = e0 + t; e < e1; e += 1024) {
        int s = src[e];
        int d = dst[e];
        int bin = d / PNODES;
        unsigned int pos = atomicAdd(&cur[bin], 1u);
        binned[pos] = (unsigned int)(d - bin * PNODES) | ((unsigned int)s << 16);
    }
    // appended sreduce: cnt_s from the (complete, hist40-written) SH array
    int w = blockIdx.x * WPB + t;
    if (t < WPB && w < NW) {
        unsigned int run = 0;
#pragma unroll 8
        for (int b = 0; b < B1; b++) run += SH[(size_t)b * NW + w];  // SWAR
        int4 c;
        c.x = (int)(run & 0xFFu); c.y = (int)((run >> 8) & 0xFFu);
        c.z = (int)((run >> 16) & 0xFFu); c.w = (int)(run >> 24);
        ((int4*)cnt_s)[w] = c;
    }
}

__global__ __launch_bounds__(1024) void scatter2_kernel(
    const unsigned int* __restrict__ binned, const unsigned int* __restrict__ binTot,
    unsigned short* __restrict__ bucket, int* __restrict__ cnt_d,
    int* __restrict__ ovf_cnt, int2* __restrict__ ovf) {
    __shared__ unsigned short bk[SN * CAP];  // 60 KB
    __shared__ unsigned int cur[SN];         // 2.5 KB
    __shared__ unsigned int bb[BINS];
    int t = (int)threadIdx.x;
    int j = (int)blockIdx.x >> 1;
    int h = (int)blockIdx.x & 1;
    if (t < BINS) bb[t] = binTot[t];
    __syncthreads();
    if (t == 0) {
        unsigned int r = 0;
        for (int q = 0; q < BINS; q++) { unsigned int v = bb[q]; bb[q] = r; r += v; }
    }
    for (int i = t; i < SN; i += 1024) cur[i] = 0u;
    __syncthreads();
    unsigned int b0 = bb[j];
    unsigned int n = binTot[j];
    int lo = h * SN;
    int nbeg = j * PNODES + lo;
    for (unsigned int i = t; i < n; i += 1024) {
        unsigned int v = binned[b0 + i];
        int dl = (int)(v & 0xFFFFu);
        int dl2 = dl - lo;
        if ((unsigned)dl2 < (unsigned)SN) {
            unsigned int s = v >> 16;
            unsigned int q = atomicAdd(&cur[dl2], 1u);
            if (q < CAP) {
                bk[dl2 * CAP + q] = (unsigned short)s;
            } else {
                int o = atomicAdd(ovf_cnt, 1);
                if (o < OVF_CAP) ovf[o] = make_int2(j * PNODES + dl, (int)s);
            }
        }
    }
    __syncthreads();
    uint4* gb = (uint4*)(bucket + (size_t)nbeg * CAP);
    const uint4* lb = (const uint4*)bk;
    const int n16 = SN * CAP * 2 / 16;   // 3750 uint4
    for (int i = t; i < n16; i += 1024) gb[i] = lb[i];
    for (int i = t; i < SN; i += 1024) cnt_d[nbeg + i] = (int)cur[i];
}

// ---------------- fused: rs arrays + xs = bf16(x * rs_out), ROW-MAJOR ----------------
__global__ void prescale_kernel(const float4* __restrict__ x, const int* __restrict__ cnt_s,
                                const int* __restrict__ cnt_d,
                                float* __restrict__ rs_out, float* __restrict__ rs_in,
                                ushort4* __restrict__ xs4, int nN) {
    int node = blockIdx.x * 8 + (threadIdx.x >> 5);
    int c = threadIdx.x & 31;
    if (node >= nN) return;
    float rs_o = 0.0f;
    if (c == 0) {
        rs_o = rsqrtf(fmaxf((float)cnt_s[node], 1.0f));
        rs_out[node] = rs_o;
        rs_in[node] = rsqrtf(fmaxf((float)cnt_d[node], 1.0f));
    }
    rs_o = __shfl(rs_o, threadIdx.x & 32);  // broadcast from node's lane 0 / 32
    float4 v = x[(size_t)node * 32 + c];
    ushort4 o;
    o.x = f2bf(v.x * rs_o);
    o.y = f2bf(v.y * rs_o);
    o.z = f2bf(v.z * rs_o);
    o.w = f2bf(v.w * rs_o);
    xs4[(size_t)node * 32 + c] = o;   // row-major: node row = 256 B
}

// ---------------- W hi/lo split into MFMA B-fragment layout ----------------
__global__ void wsplit_kernel(const float* __restrict__ W1, bf16_t* __restrict__ Wf1,
                              const float* __restrict__ W2, bf16_t* __restrict__ Wf2) {
    const float* W = blockIdx.y ? W2 : W1;
    bf16_t* Wf = blockIdx.y ? Wf2 : Wf1;
    int flat = blockIdx.x * 256 + (int)threadIdx.x;   // 0..2047 (grid.x = 8)
    int lane = flat & 63;
    int c = (flat >> 6) & 7;
    int ks = flat >> 9;
    int n = c * 16 + (lane & 15);
    int kb = ks * 32 + (lane >> 4) * 8;
#pragma unroll
    for (int j = 0; j < 8; j++) {
        float w = W[(size_t)(kb + j) * D + n];
        bf16_t hi = f2bf(w);
        bf16_t lo = f2bf(w - bf2f(hi));
        Wf[(size_t)flat * 8 + j] = hi;
        Wf[(size_t)(2048 + flat) * 8 + j] = lo;
    }
}

// =============== fused gather + ovf-patch + MFMA gemm, 16 threads/node ===============
// r9 structural cap: 8 thr/node -> 6250 waves = 24.4 waves/CU (76%). Now 32
// lanes/row (uint2 8B loads, same 256 B/row traffic) -> 12500 waves, pinned at
// the 32-wave/CU cap (100%). Bucket rows pre-staged in LDS so the per-edge
// chain is ds_read(idx) -> global(row), not global -> global. launch_bounds
// (1024, 8) holds VGPR <= 64 so 2 blocks/CU co-reside.
#define LDW 132
template <bool RELU_OUTSCALE, bool OUT_BF16>
__global__ __launch_bounds__(1024, 8) void fused_layer_kernel(
    const uint2* __restrict__ xs2,           // bf16 row-major src features: 32 uint2/row
    const int* __restrict__ cnt_d,
    const unsigned short* __restrict__ bucket,
    const int* __restrict__ ovf_cnt, const int2* __restrict__ ovf,
    const float* __restrict__ rs_in, const float* __restrict__ rs_out,
    const bf16_t* __restrict__ Wf, const float* __restrict__ bias,
    void* __restrict__ outp, int nN) {
    __shared__ float sA[32 * LDW];           // 16.9 KB
    __shared__ unsigned short sb[32 * CAP];  // 3 KB staged bucket rows
    int tid = (int)threadIdx.x;
    int n0 = blockIdx.x * 32;

    // ---- phase 0: stage 32 bucket rows (32 x 6 uint4) ----
    if (tid < 32 * 6) {
        int ln = tid / 6, w = tid % 6;
        int node = n0 + ln;
        uint4 v = make_uint4(0u, 0u, 0u, 0u);
        if (node < nN) v = ((const uint4*)(bucket + (size_t)node * CAP))[w];
        ((uint4*)sb)[ln * 6 + w] = v;
    }
    __syncthreads();

    // ---- phase 1: gather, 1 row/thread-slice (32 lanes x 4 cols each) ----
    int row = tid >> 5;        // 0..31 local node
    int lane32 = tid & 31;     // col chunk: cols [lane32*4, lane32*4+4)
    int node = n0 + row;
    float a0 = 0.f, a1 = 0.f, a2 = 0.f, a3 = 0.f;
#define ACC4(v)                                  \
    a0 += u2f_lo(v.x); a1 += u2f_hi(v.x);        \
    a2 += u2f_lo(v.y); a3 += u2f_hi(v.y);
    if (node < nN) {
        const unsigned short* bkl = sb + row * CAP;
        int cnt = min(cnt_d[node], CAP);
        int e = 0;
        for (; e + 3 < cnt; e += 4) {
            int s0 = bkl[e], s1 = bkl[e + 1], s2 = bkl[e + 2], s3 = bkl[e + 3];
            uint2 v0 = xs2[(size_t)s0 * 32 + lane32];
            uint2 v1 = xs2[(size_t)s1 * 32 + lane32];
            uint2 v2 = xs2[(size_t)s2 * 32 + lane32];
            uint2 v3 = xs2[(size_t)s3 * 32 + lane32];
            ACC4(v0) ACC4(v1) ACC4(v2) ACC4(v3)
        }
        for (; e < cnt; e++) {
            int s0 = bkl[e];
            uint2 v0 = xs2[(size_t)s0 * 32 + lane32];
            ACC4(v0)
        }
    }
#undef ACC4
    {
        float* rp = sA + row * LDW + lane32 * 4;
        rp[0] = a0; rp[1] = a1; rp[2] = a2; rp[3] = a3;
    }

    // ---- overflow patch (uniform branch; no-op when list empty) ----
    int novf = min(*ovf_cnt, OVF_CAP);
    if (novf > 0) {
        __syncthreads();
        for (int i = tid; i < novf; i += 1024) {
            int2 ds = ovf[i];
            int ln = ds.x - n0;
            if ((unsigned)ln < 32u) {
                const uint2* xr = xs2 + (size_t)ds.y * 32;
                for (int c = 0; c < 32; c++) {
                    uint2 v = xr[c];
                    float* q = sA + ln * LDW + c * 4;
                    atomicAdd(q + 0, u2f_lo(v.x)); atomicAdd(q + 1, u2f_hi(v.x));
                    atomicAdd(q + 2, u2f_lo(v.y)); atomicAdd(q + 3, u2f_hi(v.y));
                }
            }
        }
    }
    __syncthreads();

    // ---- phase 2: split-bf16 MFMA (3-term Markidis); 16 waves = 2 tiles x 8 col-jobs ----
    int lane = tid & 63;
    int wave = tid >> 6;       // 0..15
    int tile = wave >> 3;      // 0..1: 16-node tile
    int job = wave & 7;        // 0..7: 16-col group
    int ar = lane & 15;        // A row within tile
    int kg = lane >> 4;        // k-subchunk of 8
    const float* ap = sA + (tile * 16 + ar) * LDW + kg * 8;
    short8v ahi[4], alo[4];
#pragma unroll
    for (int ks = 0; ks < 4; ks++) {
        float4 p0 = *(const float4*)(ap + ks * 32);
        float4 p1 = *(const float4*)(ap + ks * 32 + 4);
        float av[8] = {p0.x, p0.y, p0.z, p0.w, p1.x, p1.y, p1.z, p1.w};
#pragma unroll
        for (int j = 0; j < 8; j++) {
            bf16_t hh = f2bf(av[j]);
            ahi[ks][j] = (short)hh;
            alo[ks][j] = (short)f2bf(av[j] - bf2f(hh));
        }
    }

    f32x4 acc = (f32x4){0.f, 0.f, 0.f, 0.f};
    const short8v* Bh = (const short8v*)Wf;        // 2048 hi frags
    const short8v* Bl = Bh + 2048;                 // 2048 lo frags
#pragma unroll
    for (int ks = 0; ks < 4; ks++) {
        int off = (ks * 8 + job) * 64 + lane;
        short8v wh = Bh[off];
        short8v wl = Bl[off];
        acc = __builtin_amdgcn_mfma_f32_16x16x32_bf16(ahi[ks], wh, acc, 0, 0, 0);
        acc = __builtin_amdgcn_mfma_f32_16x16x32_bf16(alo[ks], wh, acc, 0, 0, 0);
        acc = __builtin_amdgcn_mfma_f32_16x16x32_bf16(ahi[ks], wl, acc, 0, 0, 0);
    }

    // ---- epilogue: col = job*16 + (lane&15), node = n0 + tile*16 + kg*4 + r ----
    int ocol = lane & 15;
    int col = job * 16 + ocol;
    float bv = bias[col];
#pragma unroll
    for (int r = 0; r < 4; r++) {
        int onode = n0 + tile * 16 + kg * 4 + r;
        if (onode >= nN) continue;
        float ri = rs_in[onode];
        float v = acc[r] * ri + bv;
        if (RELU_OUTSCALE) v = fmaxf(v, 0.0f) * rs_out[onode];
        if (OUT_BF16) {
            ((bf16_t*)outp)[(size_t)onode * D + col] = f2bf(v);
        } else {
            ((float*)outp)[(size_t)onode * D + col] = v;
        }
    }
}
#undef LDW

static inline size_t align16(size_t x) { return (x + 15) & ~(size_t)15; }

extern "C" void kernel_launch(void* const* d_in, const int* in_sizes, int n_in,
                              void* d_out, int out_size, void* d_ws, size_t ws_size,
                              hipStream_t stream) {
    const float* x   = (const float*)d_in[0];
    const int*   src = (const int*)d_in[1];
    const int*   dst = (const int*)d_in[2];
    const float* W1  = (const float*)d_in[3];
    const float* b1  = (const float*)d_in[4];
    const float* W2  = (const float*)d_in[5];
    const float* b2  = (const float*)d_in[6];
    float* out = (float*)d_out;

    char* p = (char*)d_ws;
    int*            cnt_s   = (int*)p;            p += align16(N_NODES * sizeof(int));
    int*            cnt_d   = (int*)p;            p += align16(N_NODES * sizeof(int));
    int*            ovf_cnt = (int*)p;            p += align16(16 * sizeof(int));
    int2*           ovf     = (int2*)p;           p += align16((size_t)OVF_CAP * sizeof(int2));
    unsigned short* bucket  = (unsigned short*)p; p += align16((size_t)N_NODES * CAP * sizeof(unsigned short));
    float*          rs_out  = (float*)p;          p += align16(N_NODES * sizeof(float));
    float*          rs_in   = (float*)p;          p += align16(N_NODES * sizeof(float));
    bf16_t*         Wf1     = (bf16_t*)p;         p += align16((size_t)2 * 2048 * 8 * sizeof(bf16_t));
    bf16_t*         Wf2     = (bf16_t*)p;         p += align16((size_t)2 * 2048 * 8 * sizeof(bf16_t));
    unsigned int*   H40     = (unsigned int*)p;   p += align16((size_t)B1 * BINS * sizeof(unsigned int));
    unsigned int*   OFF40   = (unsigned int*)p;   p += align16((size_t)B1 * BINS * sizeof(unsigned int));
    unsigned int*   binTot  = (unsigned int*)p;   p += align16(BINS * sizeof(unsigned int));
    unsigned int*   binned  = (unsigned int*)p;   p += align16((size_t)N_EDGES * sizeof(unsigned int));
    bf16_t*         xs      = (bf16_t*)p;         p += align16((size_t)N_NODES * D * sizeof(bf16_t));
    bf16_t*         hs      = (bf16_t*)p;         // 12.8 MB
    // SH (B1*NW u32 = 12.8 MB) aliases hs: hist40 writes / place40 reads SH
    // strictly before fused layer 1 writes hs.
    unsigned int*   SH      = (unsigned int*)hs;

    // weight hi/lo split into MFMA fragment layout (both layers, one tiny launch)
    wsplit_kernel<<<dim3(8, 2), 256, 0, stream>>>(W1, Wf1, W2, Wf2);

    // two-phase binned scatter (hist40 zeroes ovf_cnt; place40 folds sreduce)
    hist40_kernel<<<B1, 1024, 0, stream>>>(src, dst, H40, SH, ovf_cnt, N_EDGES);
    scan40_kernel<<<BINS, B1, 0, stream>>>(H40, OFF40, binTot);
    place40_kernel<<<B1, 1024, 0, stream>>>(src, dst, OFF40, binTot, binned, SH, cnt_s, N_EDGES);
    scatter2_kernel<<<BINS * 2, 1024, 0, stream>>>(binned, binTot, bucket, cnt_d, ovf_cnt, ovf);

    // rs arrays + xs = bf16(x * rs_out), row-major
    prescale_kernel<<<(N_NODES + 7) / 8, 256, 0, stream>>>((const float4*)x, cnt_s, cnt_d,
                                                           rs_out, rs_in, (ushort4*)xs, N_NODES);

    int fgrid = (N_NODES + 31) / 32;   // 32 nodes per fused block

    // layer 1: hs = bf16( relu(rs_in * (gather(xs) @ W1) + b1) * rs_out )
    fused_layer_kernel<true, true><<<fgrid, 1024, 0, stream>>>(
        (const uint2*)xs, cnt_d, bucket, ovf_cnt, ovf, rs_in, rs_out, Wf1, b1, hs, N_NODES);

    // layer 2: out = rs_in * (gather(hs) @ W2) + b2   (fp32 row-major)
    fused_layer_kernel<false, false><<<fgrid, 1024, 0, stream>>>(
        (const uint2*)hs, cnt_d, bucket, ovf_cnt, ovf, rs_in, rs_out, Wf2, b2, out, N_NODES);
}

// Round 11
// 216.255 us; speedup vs baseline: 1.1472x; 1.1472x over previous
//
#include <hip/hip_runtime.h>

#define N_NODES 50000
#define N_EDGES 800000
#define D 128
#define CAP 48      // bucket capacity per dst node (max in-degree ~45 for this dataset)
#define OVF_CAP 4096

#define BINS 40     // dst partitions
#define PNODES 1250 // nodes per partition = 50000/40
#define SN 625      // nodes per scatter2 block (2 blocks per bin)
#define B1 256      // binning blocks -> 1 block/CU
#define CH1 ((N_EDGES + B1 - 1) / B1)   // 3125 edges per chunk
#define NW (N_NODES / 4)                // packed byte-counter words = 12500
#define WPB ((NW + B1 - 1) / B1)        // sreduce words per place40 block = 49

typedef unsigned short bf16_t;
typedef __attribute__((ext_vector_type(8))) short short8v;   // 8 bf16 = 4 VGPR (MFMA A/B frag)
typedef __attribute__((ext_vector_type(4))) float f32x4;     // MFMA C/D frag

__device__ inline float bf2f(bf16_t u) {
    union { unsigned int i; float f; } v;
    v.i = ((unsigned int)u) << 16;
    return v.f;
}
__device__ inline bf16_t f2bf(float f) {
    union { float f; unsigned int i; } v;
    v.f = f;
    unsigned int u = v.i;
    unsigned int r = (u + 0x7FFFu + ((u >> 16) & 1u)) >> 16;  // RNE
    return (bf16_t)r;
}
// bf16 pair packed in a u32 (little-endian: lo half = even col, hi half = odd col)
__device__ inline float u2f_lo(unsigned int u) {
    union { unsigned int i; float f; } x; x.i = u << 16; return x.f;
}
__device__ inline float u2f_hi(unsigned int u) {
    union { unsigned int i; float f; } x; x.i = u & 0xFFFF0000u; return x.f;
}

// =============== two-phase binned scatter (r10 destarved version, kept) ===============
__global__ __launch_bounds__(1024) void hist40_kernel(const int* __restrict__ src,
                                                      const int* __restrict__ dst,
                                                      unsigned int* __restrict__ H40,
                                                      unsigned int* __restrict__ SH,
                                                      int* __restrict__ ovf_cnt, int nE) {
    __shared__ unsigned int hb[BINS];
    __shared__ unsigned int hs[NW];   // 50 KB src byte counters
    if (blockIdx.x == 0 && threadIdx.x == 0) ovf_cnt[0] = 0;
    for (int i = threadIdx.x; i < NW; i += 1024) hs[i] = 0u;
    if (threadIdx.x < BINS) hb[threadIdx.x] = 0u;
    __syncthreads();
    int e0 = blockIdx.x * CH1;
    int e1 = min(e0 + CH1, nE);
    for (int e = e0 + (int)threadIdx.x; e < e1; e += 1024) {
        int s = src[e];
        int d = dst[e];
        atomicAdd(&hs[s >> 2], 1u << (8 * (s & 3)));   // per-chunk count < 256
        atomicAdd(&hb[d / PNODES], 1u);
    }
    __syncthreads();
    if (threadIdx.x < BINS) H40[blockIdx.x * BINS + threadIdx.x] = hb[threadIdx.x];
    unsigned int* SHb = SH + (size_t)blockIdx.x * NW;
    for (int i = threadIdx.x; i < NW; i += 1024) SHb[i] = hs[i];
}

// parallel scan over B1 chunks per bin: block = bin, Hillis-Steele in LDS
__global__ __launch_bounds__(B1) void scan40_kernel(const unsigned int* __restrict__ H40,
                                                    unsigned int* __restrict__ OFF40,
                                                    unsigned int* __restrict__ binTot) {
    __shared__ unsigned int sc[B1];
    int j = (int)blockIdx.x;
    int t = (int)threadIdx.x;
    unsigned int own = H40[t * BINS + j];
    sc[t] = own;
    __syncthreads();
    for (int off = 1; off < B1; off <<= 1) {
        unsigned int v = (t >= off) ? sc[t - off] : 0u;
        __syncthreads();
        sc[t] += v;
        __syncthreads();
    }
    OFF40[t * BINS + j] = sc[t] - own;   // exclusive prefix (within bin)
    if (t == B1 - 1) binTot[j] = sc[t];
}

__global__ __launch_bounds__(1024) void place40_kernel(const int* __restrict__ src,
                                                       const int* __restrict__ dst,
                                                       const unsigned int* __restrict__ OFF40,
                                                       const unsigned int* __restrict__ binTot,
                                                       unsigned int* __restrict__ binned,
                                                       const unsigned int* __restrict__ SH,
                                                       int* __restrict__ cnt_s, int nE) {
    __shared__ unsigned int cur[BINS];
    __shared__ unsigned int bb[BINS];
    int t = (int)threadIdx.x;
    if (t < BINS) bb[t] = binTot[t];
    __syncthreads();
    if (t == 0) {
        unsigned int r = 0;
        for (int q = 0; q < BINS; q++) { unsigned int v = bb[q]; bb[q] = r; r += v; }
    }
    __syncthreads();
    if (t < BINS) cur[t] = OFF40[blockIdx.x * BINS + t] + bb[t];
    __syncthreads();
    int e0 = blockIdx.x * CH1;
    int e1 = min(e0 + CH1, nE);
    for (int e = e0 + t; e < e1; e += 1024) {
        int s = src[e];
        int d = dst[e];
        int bin = d / PNODES;
        unsigned int pos = atomicAdd(&cur[bin], 1u);
        binned[pos] = (unsigned int)(d - bin * PNODES) | ((unsigned int)s << 16);
    }
    // appended sreduce: cnt_s from the (complete, hist40-written) SH array
    int w = blockIdx.x * WPB + t;
    if (t < WPB && w < NW) {
        unsigned int run = 0;
#pragma unroll 8
        for (int b = 0; b < B1; b++) run += SH[(size_t)b * NW + w];  // SWAR
        int4 c;
        c.x = (int)(run & 0xFFu); c.y = (int)((run >> 8) & 0xFFu);
        c.z = (int)((run >> 16) & 0xFFu); c.w = (int)(run >> 24);
        ((int4*)cnt_s)[w] = c;
    }
}

__global__ __launch_bounds__(1024) void scatter2_kernel(
    const unsigned int* __restrict__ binned, const unsigned int* __restrict__ binTot,
    unsigned short* __restrict__ bucket, int* __restrict__ cnt_d,
    int* __restrict__ ovf_cnt, int2* __restrict__ ovf) {
    __shared__ unsigned short bk[SN * CAP];  // 60 KB
    __shared__ unsigned int cur[SN];         // 2.5 KB
    __shared__ unsigned int bb[BINS];
    int t = (int)threadIdx.x;
    int j = (int)blockIdx.x >> 1;
    int h = (int)blockIdx.x & 1;
    if (t < BINS) bb[t] = binTot[t];
    __syncthreads();
    if (t == 0) {
        unsigned int r = 0;
        for (int q = 0; q < BINS; q++) { unsigned int v = bb[q]; bb[q] = r; r += v; }
    }
    for (int i = t; i < SN; i += 1024) cur[i] = 0u;
    __syncthreads();
    unsigned int b0 = bb[j];
    unsigned int n = binTot[j];
    int lo = h * SN;
    int nbeg = j * PNODES + lo;
    for (unsigned int i = t; i < n; i += 1024) {
        unsigned int v = binned[b0 + i];
        int dl = (int)(v & 0xFFFFu);
        int dl2 = dl - lo;
        if ((unsigned)dl2 < (unsigned)SN) {
            unsigned int s = v >> 16;
            unsigned int q = atomicAdd(&cur[dl2], 1u);
            if (q < CAP) {
                bk[dl2 * CAP + q] = (unsigned short)s;
            } else {
                int o = atomicAdd(ovf_cnt, 1);
                if (o < OVF_CAP) ovf[o] = make_int2(j * PNODES + dl, (int)s);
            }
        }
    }
    __syncthreads();
    uint4* gb = (uint4*)(bucket + (size_t)nbeg * CAP);
    const uint4* lb = (const uint4*)bk;
    const int n16 = SN * CAP * 2 / 16;   // 3750 uint4
    for (int i = t; i < n16; i += 1024) gb[i] = lb[i];
    for (int i = t; i < SN; i += 1024) cnt_d[nbeg + i] = (int)cur[i];
}

// ---------------- fused: rs arrays + xs = bf16(x * rs_out), ROW-MAJOR ----------------
__global__ void prescale_kernel(const float4* __restrict__ x, const int* __restrict__ cnt_s,
                                const int* __restrict__ cnt_d,
                                float* __restrict__ rs_out, float* __restrict__ rs_in,
                                ushort4* __restrict__ xs4, int nN) {
    int node = blockIdx.x * 8 + (threadIdx.x >> 5);
    int c = threadIdx.x & 31;
    if (node >= nN) return;
    float rs_o = 0.0f;
    if (c == 0) {
        rs_o = rsqrtf(fmaxf((float)cnt_s[node], 1.0f));
        rs_out[node] = rs_o;
        rs_in[node] = rsqrtf(fmaxf((float)cnt_d[node], 1.0f));
    }
    rs_o = __shfl(rs_o, threadIdx.x & 32);  // broadcast from node's lane 0 / 32
    float4 v = x[(size_t)node * 32 + c];
    ushort4 o;
    o.x = f2bf(v.x * rs_o);
    o.y = f2bf(v.y * rs_o);
    o.z = f2bf(v.z * rs_o);
    o.w = f2bf(v.w * rs_o);
    xs4[(size_t)node * 32 + c] = o;   // row-major: node row = 256 B
}

// ---------------- W hi/lo split into MFMA B-fragment layout ----------------
__global__ void wsplit_kernel(const float* __restrict__ W1, bf16_t* __restrict__ Wf1,
                              const float* __restrict__ W2, bf16_t* __restrict__ Wf2) {
    const float* W = blockIdx.y ? W2 : W1;
    bf16_t* Wf = blockIdx.y ? Wf2 : Wf1;
    int flat = blockIdx.x * 256 + (int)threadIdx.x;   // 0..2047 (grid.x = 8)
    int lane = flat & 63;
    int c = (flat >> 6) & 7;
    int ks = flat >> 9;
    int n = c * 16 + (lane & 15);
    int kb = ks * 32 + (lane >> 4) * 8;
#pragma unroll
    for (int j = 0; j < 8; j++) {
        float w = W[(size_t)(kb + j) * D + n];
        bf16_t hi = f2bf(w);
        bf16_t lo = f2bf(w - bf2f(hi));
        Wf[(size_t)flat * 8 + j] = hi;
        Wf[(size_t)(2048 + flat) * 8 + j] = lo;
    }
}

// =============== fused gather + ovf-patch + MFMA gemm, 512 threads ===============
// REVERTED to the r9 shape (measured ~36 us). r10's 16-thr/node restructure
// regressed to 66 us: 16-col-per-wave epilogue wrote 32 B half-lines (WRITE
// 12.5->62.7 MB partial-line thrash), lane32*4 LDS stores hit 8-way bank
// conflicts (800K), write-allocate fetches +50 MB. This shape writes whole
// lines (64-col halves), conflict-free LDS, uint4 full-row gather.
#define LDW 132
template <bool RELU_OUTSCALE, bool OUT_BF16>
__global__ __launch_bounds__(512) void fused_layer_kernel(
    const uint4* __restrict__ xsrc,          // bf16 row-major src features: 16 uint4/row
    const int* __restrict__ cnt_d,
    const unsigned short* __restrict__ bucket,
    const int* __restrict__ ovf_cnt, const int2* __restrict__ ovf,
    const float* __restrict__ rs_in, const float* __restrict__ rs_out,
    const bf16_t* __restrict__ Wf, const float* __restrict__ bias,
    void* __restrict__ outp, int nN) {
    __shared__ float sA[64 * LDW];   // 33.8 KB
    int tid = (int)threadIdx.x;
    int n0 = blockIdx.x * 64;
    int lane16 = tid & 15;
    int grp = tid >> 4;        // 0..31

    // ---- phase 1: gather 64 node rows into sA (2 rows/thread) ----
#define ACC8(v)                                              \
    a[0] += u2f_lo(v.x); a[1] += u2f_hi(v.x);                \
    a[2] += u2f_lo(v.y); a[3] += u2f_hi(v.y);                \
    a[4] += u2f_lo(v.z); a[5] += u2f_hi(v.z);                \
    a[6] += u2f_lo(v.w); a[7] += u2f_hi(v.w);
#pragma unroll
    for (int r = 0; r < 2; r++) {
        int ln = r * 32 + grp;     // local node 0..63
        int node = n0 + ln;
        float a[8];
#pragma unroll
        for (int k = 0; k < 8; k++) a[k] = 0.f;
        if (node < nN) {
            const unsigned short* bk = bucket + (size_t)node * CAP;
            int cnt = min(cnt_d[node], CAP);
            int e = 0;
            for (; e + 3 < cnt; e += 4) {
                int s0 = bk[e], s1 = bk[e + 1], s2 = bk[e + 2], s3 = bk[e + 3];
                uint4 v0 = xsrc[(size_t)s0 * 16 + lane16];
                uint4 v1 = xsrc[(size_t)s1 * 16 + lane16];
                uint4 v2 = xsrc[(size_t)s2 * 16 + lane16];
                uint4 v3 = xsrc[(size_t)s3 * 16 + lane16];
                ACC8(v0) ACC8(v1) ACC8(v2) ACC8(v3)
            }
            for (; e < cnt; e++) {
                int s0 = bk[e];
                uint4 v0 = xsrc[(size_t)s0 * 16 + lane16];
                ACC8(v0)
            }
        }
        float* row = sA + ln * LDW + lane16 * 8;
#pragma unroll
        for (int k = 0; k < 8; k++) row[k] = a[k];
    }
#undef ACC8

    // ---- overflow patch (uniform branch; no-op when list empty) ----
    int novf = min(*ovf_cnt, OVF_CAP);
    if (novf > 0) {
        __syncthreads();
        for (int i = tid; i < novf; i += 512) {
            int2 ds = ovf[i];
            int ln = ds.x - n0;
            if ((unsigned)ln < 64u) {
                const uint4* xr = xsrc + (size_t)ds.y * 16;
                for (int c = 0; c < 16; c++) {
                    uint4 v = xr[c];
                    float* q = sA + ln * LDW + c * 8;
                    atomicAdd(q + 0, u2f_lo(v.x)); atomicAdd(q + 1, u2f_hi(v.x));
                    atomicAdd(q + 2, u2f_lo(v.y)); atomicAdd(q + 3, u2f_hi(v.y));
                    atomicAdd(q + 4, u2f_lo(v.z)); atomicAdd(q + 5, u2f_hi(v.z));
                    atomicAdd(q + 6, u2f_lo(v.w)); atomicAdd(q + 7, u2f_hi(v.w));
                }
            }
        }
    }
    __syncthreads();

    // ---- phase 2: split-bf16 MFMA from LDS; wave pair per 16-node tile ----
    int lane = tid & 63;
    int wave = tid >> 6;       // 0..7
    int tile = wave >> 1;      // 0..3: node tile
    int half = wave & 1;       // 0..1: column half (64 cols)
    int ar = lane & 15;        // A row within tile
    int kg = lane >> 4;        // k-subchunk of 8
    const float* ap = sA + (tile * 16 + ar) * LDW + kg * 8;
    short8v ahi[4], alo[4];
#pragma unroll
    for (int ks = 0; ks < 4; ks++) {
#pragma unroll
        for (int j = 0; j < 8; j++) {
            float av = ap[ks * 32 + j];
            bf16_t h = f2bf(av);
            ahi[ks][j] = (short)h;
            alo[ks][j] = (short)f2bf(av - bf2f(h));
        }
    }

    f32x4 acc[4];
#pragma unroll
    for (int c = 0; c < 4; c++) acc[c] = (f32x4){0.f, 0.f, 0.f, 0.f};

    const short8v* Bh = (const short8v*)Wf;        // 2048 hi frags
    const short8v* Bl = Bh + 2048;                 // 2048 lo frags
#pragma unroll
    for (int ks = 0; ks < 4; ks++) {
#pragma unroll
        for (int c = 0; c < 4; c++) {
            int off = (ks * 8 + half * 4 + c) * 64 + lane;
            short8v wh = Bh[off];
            short8v wl = Bl[off];
            acc[c] = __builtin_amdgcn_mfma_f32_16x16x32_bf16(ahi[ks], wh, acc[c], 0, 0, 0);
            acc[c] = __builtin_amdgcn_mfma_f32_16x16x32_bf16(alo[ks], wh, acc[c], 0, 0, 0);
            acc[c] = __builtin_amdgcn_mfma_f32_16x16x32_bf16(ahi[ks], wl, acc[c], 0, 0, 0);
        }
    }

    // ---- epilogue: col = half*64 + c*16 + (lane&15), node = n0 + tile*16 + kg*4 + r ----
    int ocol = lane & 15;
#pragma unroll
    for (int r = 0; r < 4; r++) {
        int node = n0 + tile * 16 + kg * 4 + r;
        if (node >= nN) continue;
        float ri = rs_in[node];
        float ro = RELU_OUTSCALE ? rs_out[node] : 1.0f;
#pragma unroll
        for (int c = 0; c < 4; c++) {
            int col = half * 64 + c * 16 + ocol;
            float v = acc[c][r] * ri + bias[col];
            if (RELU_OUTSCALE) v = fmaxf(v, 0.0f) * ro;
            if (OUT_BF16) {
                ((bf16_t*)outp)[(size_t)node * D + col] = f2bf(v);
            } else {
                ((float*)outp)[(size_t)node * D + col] = v;
            }
        }
    }
}
#undef LDW

static inline size_t align16(size_t x) { return (x + 15) & ~(size_t)15; }

extern "C" void kernel_launch(void* const* d_in, const int* in_sizes, int n_in,
                              void* d_out, int out_size, void* d_ws, size_t ws_size,
                              hipStream_t stream) {
    const float* x   = (const float*)d_in[0];
    const int*   src = (const int*)d_in[1];
    const int*   dst = (const int*)d_in[2];
    const float* W1  = (const float*)d_in[3];
    const float* b1  = (const float*)d_in[4];
    const float* W2  = (const float*)d_in[5];
    const float* b2  = (const float*)d_in[6];
    float* out = (float*)d_out;

    char* p = (char*)d_ws;
    int*            cnt_s   = (int*)p;            p += align16(N_NODES * sizeof(int));
    int*            cnt_d   = (int*)p;            p += align16(N_NODES * sizeof(int));
    int*            ovf_cnt = (int*)p;            p += align16(16 * sizeof(int));
    int2*           ovf     = (int2*)p;           p += align16((size_t)OVF_CAP * sizeof(int2));
    unsigned short* bucket  = (unsigned short*)p; p += align16((size_t)N_NODES * CAP * sizeof(unsigned short));
    float*          rs_out  = (float*)p;          p += align16(N_NODES * sizeof(float));
    float*          rs_in   = (float*)p;          p += align16(N_NODES * sizeof(float));
    bf16_t*         Wf1     = (bf16_t*)p;         p += align16((size_t)2 * 2048 * 8 * sizeof(bf16_t));
    bf16_t*         Wf2     = (bf16_t*)p;         p += align16((size_t)2 * 2048 * 8 * sizeof(bf16_t));
    unsigned int*   H40     = (unsigned int*)p;   p += align16((size_t)B1 * BINS * sizeof(unsigned int));
    unsigned int*   OFF40   = (unsigned int*)p;   p += align16((size_t)B1 * BINS * sizeof(unsigned int));
    unsigned int*   binTot  = (unsigned int*)p;   p += align16(BINS * sizeof(unsigned int));
    unsigned int*   binned  = (unsigned int*)p;   p += align16((size_t)N_EDGES * sizeof(unsigned int));
    bf16_t*         xs      = (bf16_t*)p;         p += align16((size_t)N_NODES * D * sizeof(bf16_t));
    bf16_t*         hs      = (bf16_t*)p;         // 12.8 MB
    // SH (B1*NW u32 = 12.8 MB) aliases hs: hist40 writes / place40 reads SH
    // strictly before fused layer 1 writes hs.
    unsigned int*   SH      = (unsigned int*)hs;

    // weight hi/lo split into MFMA fragment layout (both layers, one tiny launch)
    wsplit_kernel<<<dim3(8, 2), 256, 0, stream>>>(W1, Wf1, W2, Wf2);

    // two-phase binned scatter (hist40 zeroes ovf_cnt; place40 folds sreduce)
    hist40_kernel<<<B1, 1024, 0, stream>>>(src, dst, H40, SH, ovf_cnt, N_EDGES);
    scan40_kernel<<<BINS, B1, 0, stream>>>(H40, OFF40, binTot);
    place40_kernel<<<B1, 1024, 0, stream>>>(src, dst, OFF40, binTot, binned, SH, cnt_s, N_EDGES);
    scatter2_kernel<<<BINS * 2, 1024, 0, stream>>>(binned, binTot, bucket, cnt_d, ovf_cnt, ovf);

    // rs arrays + xs = bf16(x * rs_out), row-major
    prescale_kernel<<<(N_NODES + 7) / 8, 256, 0, stream>>>((const float4*)x, cnt_s, cnt_d,
                                                           rs_out, rs_in, (ushort4*)xs, N_NODES);

    int fgrid = (N_NODES + 63) / 64;   // 64 nodes per fused block

    // layer 1: hs = bf16( relu(rs_in * (gather(xs) @ W1) + b1) * rs_out )
    fused_layer_kernel<true, true><<<fgrid, 512, 0, stream>>>(
        (const uint4*)xs, cnt_d, bucket, ovf_cnt, ovf, rs_in, rs_out, Wf1, b1, hs, N_NODES);

    // layer 2: out = rs_in * (gather(hs) @ W2) + b2   (fp32 row-major)
    fused_layer_kernel<false, false><<<fgrid, 512, 0, stream>>>(
        (const uint4*)hs, cnt_d, bucket, ovf_cnt, ovf, rs_in, rs_out, Wf2, b2, out, N_NODES);
}

// Round 12
// 207.248 us; speedup vs baseline: 1.1970x; 1.0435x over previous
//
#include <hip/hip_runtime.h>

#define N_NODES 50000
#define N_EDGES 800000
#define D 128
#define CAP 48      // bucket capacity per dst node (max in-degree ~45 for this dataset)
#define OVF_CAP 4096

#define BINS 40     // dst partitions (one scatter2 block each)
#define PNODES 1250 // nodes per partition = 50000/40
#define B1 64       // binning blocks (hist40/place40 share chunking)
#define CH1 ((N_EDGES + B1 - 1) / B1)   // 12500 edges per chunk
#define NW (N_NODES / 4)                // packed byte-counter words = 12500
#define WPB ((NW + B1 - 1) / B1)        // sreduce words per place40 block = 196

typedef unsigned short bf16_t;
typedef __attribute__((ext_vector_type(8))) short short8v;   // 8 bf16 = 4 VGPR (MFMA A/B frag)
typedef __attribute__((ext_vector_type(4))) float f32x4;     // MFMA C/D frag

__device__ inline float bf2f(bf16_t u) {
    union { unsigned int i; float f; } v;
    v.i = ((unsigned int)u) << 16;
    return v.f;
}
__device__ inline bf16_t f2bf(float f) {
    union { float f; unsigned int i; } v;
    v.f = f;
    unsigned int u = v.i;
    unsigned int r = (u + 0x7FFFu + ((u >> 16) & 1u)) >> 16;  // RNE
    return (bf16_t)r;
}
// bf16 pair packed in a u32 (little-endian: lo half = even col, hi half = odd col)
__device__ inline float u2f_lo(unsigned int u) {
    union { unsigned int i; float f; } x; x.i = u << 16; return x.f;
}
__device__ inline float u2f_hi(unsigned int u) {
    union { unsigned int i; float f; } x; x.i = u & 0xFFFF0000u; return x.f;
}

// =============== two-phase binned scatter (EXACT r9 source — best measured 197.3) ===============
// hist40 also zeroes ovf_cnt (replaces the hipMemsetAsync dispatch);
// place40 also reduces SH -> cnt_s (replaces the sreduce dispatch).
__global__ __launch_bounds__(1024) void hist40_kernel(const int* __restrict__ src,
                                                      const int* __restrict__ dst,
                                                      unsigned int* __restrict__ H40,
                                                      unsigned int* __restrict__ SH,
                                                      int* __restrict__ ovf_cnt, int nE) {
    __shared__ unsigned int hb[BINS];
    __shared__ unsigned int hs[NW];   // 50 KB src byte counters
    if (blockIdx.x == 0 && threadIdx.x == 0) ovf_cnt[0] = 0;
    for (int i = threadIdx.x; i < NW; i += 1024) hs[i] = 0u;
    if (threadIdx.x < BINS) hb[threadIdx.x] = 0u;
    __syncthreads();
    int e0 = blockIdx.x * CH1;
    int e1 = min(e0 + CH1, nE);
    for (int e = e0 + (int)threadIdx.x; e < e1; e += 1024) {
        int s = src[e];
        int d = dst[e];
        atomicAdd(&hs[s >> 2], 1u << (8 * (s & 3)));   // per-chunk count <= out-degree < 256
        atomicAdd(&hb[d / PNODES], 1u);
    }
    __syncthreads();
    if (threadIdx.x < BINS) H40[blockIdx.x * BINS + threadIdx.x] = hb[threadIdx.x];
    unsigned int* SHb = SH + (size_t)blockIdx.x * NW;
    for (int i = threadIdx.x; i < NW; i += 1024) SHb[i] = hs[i];
}

__global__ void scan40_kernel(const unsigned int* __restrict__ H40,
                              unsigned int* __restrict__ OFF40,
                              unsigned int* __restrict__ binBase,
                              unsigned int* __restrict__ binTot) {
    __shared__ unsigned int part[B1 * BINS];   // 10 KB
    __shared__ unsigned int tot[BINS], base[BINS];
    int j = (int)threadIdx.x;
    if (j < BINS) {
        unsigned int run = 0;
        for (int b = 0; b < B1; b++) {
            part[b * BINS + j] = run;
            run += H40[b * BINS + j];
        }
        tot[j] = run;
    }
    __syncthreads();
    if (j == 0) {
        unsigned int run = 0;
        for (int q = 0; q < BINS; q++) { base[q] = run; run += tot[q]; }
    }
    __syncthreads();
    if (j < BINS) {
        binBase[j] = base[j];
        binTot[j] = tot[j];
        for (int b = 0; b < B1; b++) OFF40[b * BINS + j] = part[b * BINS + j] + base[j];
    }
}

__global__ __launch_bounds__(1024) void place40_kernel(const int* __restrict__ src,
                                                       const int* __restrict__ dst,
                                                       const unsigned int* __restrict__ OFF40,
                                                       unsigned int* __restrict__ binned,
                                                       const unsigned int* __restrict__ SH,
                                                       int* __restrict__ cnt_s, int nE) {
    __shared__ unsigned int cur[BINS];
    if (threadIdx.x < BINS) cur[threadIdx.x] = OFF40[blockIdx.x * BINS + threadIdx.x];
    __syncthreads();
    int e0 = blockIdx.x * CH1;
    int e1 = min(e0 + CH1, nE);
    for (int e = e0 + (int)threadIdx.x; e < e1; e += 1024) {
        int s = src[e];
        int d = dst[e];
        int bin = d / PNODES;
        unsigned int pos = atomicAdd(&cur[bin], 1u);
        binned[pos] = (unsigned int)(d - bin * PNODES) | ((unsigned int)s << 16);
    }
    // appended sreduce: cnt_s from the (complete, hist40-written) SH array
    int w = blockIdx.x * WPB + (int)threadIdx.x;
    if ((int)threadIdx.x < WPB && w < NW) {
        unsigned int run = 0;
#pragma unroll 8
        for (int b = 0; b < B1; b++) run += SH[(size_t)b * NW + w];  // SWAR
        int4 c;
        c.x = (int)(run & 0xFFu); c.y = (int)((run >> 8) & 0xFFu);
        c.z = (int)((run >> 16) & 0xFFu); c.w = (int)(run >> 24);
        ((int4*)cnt_s)[w] = c;
    }
}

__global__ __launch_bounds__(1024) void scatter2_kernel(
    const unsigned int* __restrict__ binned, const unsigned int* __restrict__ binBase,
    const unsigned int* __restrict__ binTot, unsigned short* __restrict__ bucket,
    int* __restrict__ cnt_d, int* __restrict__ ovf_cnt, int2* __restrict__ ovf) {
    __shared__ unsigned short bk[PNODES * CAP];  // 120 KB
    __shared__ unsigned int cur[PNODES];         // 5 KB
    const int j = blockIdx.x;
    const int nbeg = j * PNODES;
    for (int i = threadIdx.x; i < PNODES; i += 1024) cur[i] = 0u;
    __syncthreads();
    unsigned int b0 = binBase[j];
    unsigned int n = binTot[j];
    for (unsigned int i = threadIdx.x; i < n; i += 1024) {
        unsigned int v = binned[b0 + i];
        unsigned int dl = v & 0xFFFFu;
        unsigned int s = v >> 16;
        unsigned int q = atomicAdd(&cur[dl], 1u);
        if (q < CAP) {
            bk[dl * CAP + q] = (unsigned short)s;
        } else {
            int o = atomicAdd(ovf_cnt, 1);
            if (o < OVF_CAP) ovf[o] = make_int2(nbeg + (int)dl, (int)s);
        }
    }
    __syncthreads();
    uint4* gb = (uint4*)(bucket + (size_t)nbeg * CAP);
    const uint4* lb = (const uint4*)bk;
    const int n16 = PNODES * CAP * 2 / 16;   // 7500 uint4
    for (int i = threadIdx.x; i < n16; i += 1024) gb[i] = lb[i];
    for (int i = threadIdx.x; i < PNODES; i += 1024) cnt_d[nbeg + i] = (int)cur[i];
}

// ---------------- fused: rs arrays + xs = bf16(x * rs_out), ROW-MAJOR ----------------
__global__ void prescale_kernel(const float4* __restrict__ x, const int* __restrict__ cnt_s,
                                const int* __restrict__ cnt_d,
                                float* __restrict__ rs_out, float* __restrict__ rs_in,
                                ushort4* __restrict__ xs4, int nN) {
    int node = blockIdx.x * 8 + (threadIdx.x >> 5);
    int c = threadIdx.x & 31;
    if (node >= nN) return;
    float rs_o = 0.0f;
    if (c == 0) {
        rs_o = rsqrtf(fmaxf((float)cnt_s[node], 1.0f));
        rs_out[node] = rs_o;
        rs_in[node] = rsqrtf(fmaxf((float)cnt_d[node], 1.0f));
    }
    rs_o = __shfl(rs_o, threadIdx.x & 32);  // broadcast from node's lane 0 / 32
    float4 v = x[(size_t)node * 32 + c];
    ushort4 o;
    o.x = f2bf(v.x * rs_o);
    o.y = f2bf(v.y * rs_o);
    o.z = f2bf(v.z * rs_o);
    o.w = f2bf(v.w * rs_o);
    xs4[(size_t)node * 32 + c] = o;   // row-major: node row = 256 B
}

// ---------------- W hi/lo split into MFMA B-fragment layout ----------------
__global__ void wsplit_kernel(const float* __restrict__ W1, bf16_t* __restrict__ Wf1,
                              const float* __restrict__ W2, bf16_t* __restrict__ Wf2) {
    const float* W = blockIdx.y ? W2 : W1;
    bf16_t* Wf = blockIdx.y ? Wf2 : Wf1;
    int flat = blockIdx.x * 256 + (int)threadIdx.x;   // 0..2047 (grid.x = 8)
    int lane = flat & 63;
    int c = (flat >> 6) & 7;
    int ks = flat >> 9;
    int n = c * 16 + (lane & 15);
    int kb = ks * 32 + (lane >> 4) * 8;
#pragma unroll
    for (int j = 0; j < 8; j++) {
        float w = W[(size_t)(kb + j) * D + n];
        bf16_t hi = f2bf(w);
        bf16_t lo = f2bf(w - bf2f(hi));
        Wf[(size_t)flat * 8 + j] = hi;
        Wf[(size_t)(2048 + flat) * 8 + j] = lo;
    }
}

// =============== fused gather + ovf-patch + MFMA gemm, 512 threads ===============
// r9 shape (best measured) with two surgical edits:
//  (1) 8-deep gather unroll: avg degree 16 -> 2 batches of 8 in-flight uint4
//      loads per thread (vs 4 of 4), doubling MLP without adding waves (r10/r11
//      showed more waves degrade L2 hit rate and regress).
//  (2) truncation hi-split: hi = top-16-bits (1 op vs 4); lo = RNE(av - hi)
//      exactly captures the residual -> dropped term still ~2^-17 rel.
#define LDW 132
template <bool RELU_OUTSCALE, bool OUT_BF16>
__global__ __launch_bounds__(512) void fused_layer_kernel(
    const uint4* __restrict__ xsrc,          // bf16 row-major src features: 16 uint4/row
    const int* __restrict__ cnt_d,
    const unsigned short* __restrict__ bucket,
    const int* __restrict__ ovf_cnt, const int2* __restrict__ ovf,
    const float* __restrict__ rs_in, const float* __restrict__ rs_out,
    const bf16_t* __restrict__ Wf, const float* __restrict__ bias,
    void* __restrict__ outp, int nN) {
    __shared__ float sA[64 * LDW];   // 33.8 KB
    int tid = (int)threadIdx.x;
    int n0 = blockIdx.x * 64;
    int lane16 = tid & 15;
    int grp = tid >> 4;        // 0..31

    // ---- phase 1: gather 64 node rows into sA (2 rows/thread, 8-deep unroll) ----
#define ACC8(v)                                              \
    a[0] += u2f_lo(v.x); a[1] += u2f_hi(v.x);                \
    a[2] += u2f_lo(v.y); a[3] += u2f_hi(v.y);                \
    a[4] += u2f_lo(v.z); a[5] += u2f_hi(v.z);                \
    a[6] += u2f_lo(v.w); a[7] += u2f_hi(v.w);
#pragma unroll
    for (int r = 0; r < 2; r++) {
        int ln = r * 32 + grp;     // local node 0..63
        int node = n0 + ln;
        float a[8];
#pragma unroll
        for (int k = 0; k < 8; k++) a[k] = 0.f;
        if (node < nN) {
            const unsigned short* bk = bucket + (size_t)node * CAP;
            int cnt = min(cnt_d[node], CAP);
            int e = 0;
            for (; e + 7 < cnt; e += 8) {
                int s0 = bk[e],     s1 = bk[e + 1], s2 = bk[e + 2], s3 = bk[e + 3];
                int s4 = bk[e + 4], s5 = bk[e + 5], s6 = bk[e + 6], s7 = bk[e + 7];
                uint4 v0 = xsrc[(size_t)s0 * 16 + lane16];
                uint4 v1 = xsrc[(size_t)s1 * 16 + lane16];
                uint4 v2 = xsrc[(size_t)s2 * 16 + lane16];
                uint4 v3 = xsrc[(size_t)s3 * 16 + lane16];
                uint4 v4 = xsrc[(size_t)s4 * 16 + lane16];
                uint4 v5 = xsrc[(size_t)s5 * 16 + lane16];
                uint4 v6 = xsrc[(size_t)s6 * 16 + lane16];
                uint4 v7 = xsrc[(size_t)s7 * 16 + lane16];
                ACC8(v0) ACC8(v1) ACC8(v2) ACC8(v3)
                ACC8(v4) ACC8(v5) ACC8(v6) ACC8(v7)
            }
            for (; e + 3 < cnt; e += 4) {
                int s0 = bk[e], s1 = bk[e + 1], s2 = bk[e + 2], s3 = bk[e + 3];
                uint4 v0 = xsrc[(size_t)s0 * 16 + lane16];
                uint4 v1 = xsrc[(size_t)s1 * 16 + lane16];
                uint4 v2 = xsrc[(size_t)s2 * 16 + lane16];
                uint4 v3 = xsrc[(size_t)s3 * 16 + lane16];
                ACC8(v0) ACC8(v1) ACC8(v2) ACC8(v3)
            }
            for (; e < cnt; e++) {
                int s0 = bk[e];
                uint4 v0 = xsrc[(size_t)s0 * 16 + lane16];
                ACC8(v0)
            }
        }
        float* row = sA + ln * LDW + lane16 * 8;
#pragma unroll
        for (int k = 0; k < 8; k++) row[k] = a[k];
    }
#undef ACC8

    // ---- overflow patch (uniform branch; no-op when list empty) ----
    int novf = min(*ovf_cnt, OVF_CAP);
    if (novf > 0) {
        __syncthreads();
        for (int i = tid; i < novf; i += 512) {
            int2 ds = ovf[i];
            int ln = ds.x - n0;
            if ((unsigned)ln < 64u) {
                const uint4* xr = xsrc + (size_t)ds.y * 16;
                for (int c = 0; c < 16; c++) {
                    uint4 v = xr[c];
                    float* q = sA + ln * LDW + c * 8;
                    atomicAdd(q + 0, u2f_lo(v.x)); atomicAdd(q + 1, u2f_hi(v.x));
                    atomicAdd(q + 2, u2f_lo(v.y)); atomicAdd(q + 3, u2f_hi(v.y));
                    atomicAdd(q + 4, u2f_lo(v.z)); atomicAdd(q + 5, u2f_hi(v.z));
                    atomicAdd(q + 6, u2f_lo(v.w)); atomicAdd(q + 7, u2f_hi(v.w));
                }
            }
        }
    }
    __syncthreads();

    // ---- phase 2: split-bf16 MFMA from LDS; wave pair per 16-node tile ----
    int lane = tid & 63;
    int wave = tid >> 6;       // 0..7
    int tile = wave >> 1;      // 0..3: node tile
    int half = wave & 1;       // 0..1: column half (64 cols)
    int ar = lane & 15;        // A row within tile
    int kg = lane >> 4;        // k-subchunk of 8
    const float* ap = sA + (tile * 16 + ar) * LDW + kg * 8;
    short8v ahi[4], alo[4];
#pragma unroll
    for (int ks = 0; ks < 4; ks++) {
#pragma unroll
        for (int j = 0; j < 8; j++) {
            float av = ap[ks * 32 + j];
            union { float f; unsigned int i; } uu; uu.f = av;
            unsigned short h = (unsigned short)(uu.i >> 16);   // truncation split
            union { unsigned int i; float f; } hv; hv.i = (unsigned int)h << 16;
            ahi[ks][j] = (short)h;
            alo[ks][j] = (short)f2bf(av - hv.f);
        }
    }

    f32x4 acc[4];
#pragma unroll
    for (int c = 0; c < 4; c++) acc[c] = (f32x4){0.f, 0.f, 0.f, 0.f};

    const short8v* Bh = (const short8v*)Wf;        // 2048 hi frags
    const short8v* Bl = Bh + 2048;                 // 2048 lo frags
#pragma unroll
    for (int ks = 0; ks < 4; ks++) {
#pragma unroll
        for (int c = 0; c < 4; c++) {
            int off = (ks * 8 + half * 4 + c) * 64 + lane;
            short8v wh = Bh[off];
            short8v wl = Bl[off];
            acc[c] = __builtin_amdgcn_mfma_f32_16x16x32_bf16(ahi[ks], wh, acc[c], 0, 0, 0);
            acc[c] = __builtin_amdgcn_mfma_f32_16x16x32_bf16(alo[ks], wh, acc[c], 0, 0, 0);
            acc[c] = __builtin_amdgcn_mfma_f32_16x16x32_bf16(ahi[ks], wl, acc[c], 0, 0, 0);
        }
    }

    // ---- epilogue: col = half*64 + c*16 + (lane&15), node = n0 + tile*16 + kg*4 + r ----
    int ocol = lane & 15;
#pragma unroll
    for (int r = 0; r < 4; r++) {
        int node = n0 + tile * 16 + kg * 4 + r;
        if (node >= nN) continue;
        float ri = rs_in[node];
        float ro = RELU_OUTSCALE ? rs_out[node] : 1.0f;
#pragma unroll
        for (int c = 0; c < 4; c++) {
            int col = half * 64 + c * 16 + ocol;
            float v = acc[c][r] * ri + bias[col];
            if (RELU_OUTSCALE) v = fmaxf(v, 0.0f) * ro;
            if (OUT_BF16) {
                ((bf16_t*)outp)[(size_t)node * D + col] = f2bf(v);
            } else {
                ((float*)outp)[(size_t)node * D + col] = v;
            }
        }
    }
}
#undef LDW

static inline size_t align16(size_t x) { return (x + 15) & ~(size_t)15; }

extern "C" void kernel_launch(void* const* d_in, const int* in_sizes, int n_in,
                              void* d_out, int out_size, void* d_ws, size_t ws_size,
                              hipStream_t stream) {
    const float* x   = (const float*)d_in[0];
    const int*   src = (const int*)d_in[1];
    const int*   dst = (const int*)d_in[2];
    const float* W1  = (const float*)d_in[3];
    const float* b1  = (const float*)d_in[4];
    const float* W2  = (const float*)d_in[5];
    const float* b2  = (const float*)d_in[6];
    float* out = (float*)d_out;

    char* p = (char*)d_ws;
    int*            cnt_s   = (int*)p;            p += align16(N_NODES * sizeof(int));
    int*            cnt_d   = (int*)p;            p += align16(N_NODES * sizeof(int));
    int*            ovf_cnt = (int*)p;            p += align16(16 * sizeof(int));
    int2*           ovf     = (int2*)p;           p += align16((size_t)OVF_CAP * sizeof(int2));
    unsigned short* bucket  = (unsigned short*)p; p += align16((size_t)N_NODES * CAP * sizeof(unsigned short));
    float*          rs_out  = (float*)p;          p += align16(N_NODES * sizeof(float));
    float*          rs_in   = (float*)p;          p += align16(N_NODES * sizeof(float));
    bf16_t*         Wf1     = (bf16_t*)p;         p += align16((size_t)2 * 2048 * 8 * sizeof(bf16_t));
    bf16_t*         Wf2     = (bf16_t*)p;         p += align16((size_t)2 * 2048 * 8 * sizeof(bf16_t));
    unsigned int*   H40     = (unsigned int*)p;   p += align16((size_t)B1 * BINS * sizeof(unsigned int));
    unsigned int*   OFF40   = (unsigned int*)p;   p += align16((size_t)B1 * BINS * sizeof(unsigned int));
    unsigned int*   binBase = (unsigned int*)p;   p += align16(BINS * sizeof(unsigned int));
    unsigned int*   binTot  = (unsigned int*)p;   p += align16(BINS * sizeof(unsigned int));
    unsigned int*   binned  = (unsigned int*)p;   p += align16((size_t)N_EDGES * sizeof(unsigned int));
    unsigned int*   SH      = (unsigned int*)p;   p += align16((size_t)B1 * NW * sizeof(unsigned int));
    bf16_t*         xs      = (bf16_t*)p;         p += align16((size_t)N_NODES * D * sizeof(bf16_t));
    bf16_t*         hs      = (bf16_t*)p;         // separate 12.8 MB buffer

    // weight hi/lo split into MFMA fragment layout (both layers, one tiny launch)
    wsplit_kernel<<<dim3(8, 2), 256, 0, stream>>>(W1, Wf1, W2, Wf2);

    // two-phase binned scatter (hist40 zeroes ovf_cnt; place40 folds sreduce)
    hist40_kernel<<<B1, 1024, 0, stream>>>(src, dst, H40, SH, ovf_cnt, N_EDGES);
    scan40_kernel<<<1, 64, 0, stream>>>(H40, OFF40, binBase, binTot);
    place40_kernel<<<B1, 1024, 0, stream>>>(src, dst, OFF40, binned, SH, cnt_s, N_EDGES);
    scatter2_kernel<<<BINS, 1024, 0, stream>>>(binned, binBase, binTot, bucket,
                                               cnt_d, ovf_cnt, ovf);

    // rs arrays + xs = bf16(x * rs_out), row-major
    prescale_kernel<<<(N_NODES + 7) / 8, 256, 0, stream>>>((const float4*)x, cnt_s, cnt_d,
                                                           rs_out, rs_in, (ushort4*)xs, N_NODES);

    int fgrid = (N_NODES + 63) / 64;   // 64 nodes per fused block

    // layer 1: hs = bf16( relu(rs_in * (gather(xs) @ W1) + b1) * rs_out )
    fused_layer_kernel<true, true><<<fgrid, 512, 0, stream>>>(
        (const uint4*)xs, cnt_d, bucket, ovf_cnt, ovf, rs_in, rs_out, Wf1, b1, hs, N_NODES);

    // layer 2: out = rs_in * (gather(hs) @ W2) + b2   (fp32 row-major)
    fused_layer_kernel<false, false><<<fgrid, 512, 0, stream>>>(
        (const uint4*)hs, cnt_d, bucket, ovf_cnt, ovf, rs_in, rs_out, Wf2, b2, out, N_NODES);
}